// Round 21
// baseline (263.100 us; speedup 1.0000x reference)
//
#include <hip/hip_runtime.h>
#include <math.h>

#define BB   2
#define LL   2048
#define HIDD 2048
#define NHH  16
#define HDD  128
#define QKN  4096   // q|k buffer row stride
#define THR2 11.5416f  // defer-max threshold, log2 domain (= 8 nats)
#define EST2 264    // 256-wide epilogue LDS row stride (u16): 528B rows, 16B-aligned

typedef unsigned short u16;
typedef float  f32x4 __attribute__((ext_vector_type(4)));
typedef __bf16 bf16x8 __attribute__((ext_vector_type(8)));

static __device__ __forceinline__ float exp2_fast(float x){
  return __builtin_amdgcn_exp2f(x);    // v_exp_f32 (native 2^x)
}
static __device__ __forceinline__ u16 f2bf(float x){
  unsigned u = __float_as_uint(x);
  return (u16)((u + 0x7fffu + ((u >> 16) & 1u)) >> 16);
}
static __device__ __forceinline__ float bf2f(u16 b){
  return __uint_as_float(((unsigned)b) << 16);
}
static __device__ __forceinline__ void gl_lds16(const void* g, void* l){
  __builtin_amdgcn_global_load_lds(
      (__attribute__((address_space(1))) void*)(void*)g,
      (__attribute__((address_space(3))) void*)l,
      16, 0, 0);
}

// ---------------- prep kernels ----------------

__global__ void cvt_f32_bf16_k(const float* __restrict__ src, u16* __restrict__ dst, int n4){
  int i = blockIdx.x * blockDim.x + threadIdx.x;
  if (i >= n4) return;
  float4 v = ((const float4*)src)[i];
  ushort4 o;
  o.x = f2bf(v.x); o.y = f2bf(v.y); o.z = f2bf(v.z); o.w = f2bf(v.w);
  ((ushort4*)dst)[i] = o;
}

// cos/sin table: tab[l*64+d] = (cos(th), sin(th)), th = (l/4)*exp(-d*ln(1e5)/64)
__global__ void rope_table_k(float2* __restrict__ tab){
  int idx = blockIdx.x * blockDim.x + threadIdx.x;   // 2048*64
  int l = idx >> 6, d = idx & 63;
  float fr = __expf(-(float)d * 0.17988946f);
  float th = (float)l * 0.25f * fr;
  float s, c;
  sincosf(th, &s, &c);
  tab[idx] = make_float2(c, s);
}

// fused 4x (2048^2 f32 -> transposed bf16). grid (32,32,4), 256 thr, 64x64 tiles.
__global__ __launch_bounds__(256) void transpose_cvt4_k(
    const float* __restrict__ Wq, const float* __restrict__ Wk,
    const float* __restrict__ Wv, const float* __restrict__ Wo,
    u16* __restrict__ Wt, u16* __restrict__ Wot)
{
  __shared__ u16 t[64][66];
  const int z = blockIdx.z;
  const float* src = (z == 0) ? Wq : (z == 1) ? Wk : (z == 2) ? Wv : Wo;
  u16* dst = (z == 3) ? Wot : (Wt + (size_t)z * 2048 * 2048);
  const int c0 = blockIdx.x * 64, r0 = blockIdx.y * 64;
  const int tid = threadIdx.x;

  #pragma unroll
  for (int i = 0; i < 4; i++){
    int r  = i * 16 + (tid >> 4);
    int c4 = (tid & 15) * 4;
    float4 v = *(const float4*)&src[(size_t)(r0 + r) * 2048 + c0 + c4];
    t[c4 + 0][r] = f2bf(v.x);
    t[c4 + 1][r] = f2bf(v.y);
    t[c4 + 2][r] = f2bf(v.z);
    t[c4 + 3][r] = f2bf(v.w);
  }
  __syncthreads();
  #pragma unroll
  for (int i = 0; i < 2; i++){
    int c  = i * 32 + (tid >> 3);
    int rs = (tid & 7) * 8;
    const unsigned* p = (const unsigned*)&t[c][rs];   // 4B-aligned
    unsigned w0 = p[0], w1 = p[1], w2 = p[2], w3 = p[3];
    u16* d = &dst[(size_t)(c0 + c) * 2048 + r0 + rs];
    ((unsigned*)d)[0] = w0; ((unsigned*)d)[1] = w1;
    ((unsigned*)d)[2] = w2; ((unsigned*)d)[3] = w3;
  }
}

// ---------------- GEMM1: 256x256 tile, 4-phase quadrant schedule, fused epilogue ------
// (r17-proven, session-best total). 8 waves (2M x 4N). Per phase: block C-quadrant
// (i,j) 128x128; all waves read A-half i + B-half j. Stage ledger: ph0: A1(t+1),
// ph1: B1(t+1), ph2: A0(t+2), ph3: B0(t+2). Boundary wait vmcnt(4); vmcnt(0) last.
// LDS map (bytes): A bufs [0,65536), B bufs [65536,131072).

#define STG_HALF(base_u16, src, rowbase, kt_) do {                                        \
  _Pragma("unroll")                                                                       \
  for (int i_ = 0; i_ < 2; i_++){                                                         \
    int cb0_ = i_ * 512 + wv * 64;             /* wave-uniform chunk base */              \
    int c_   = cb0_ + lane;                                                               \
    int r_   = c_ >> 3;                        /* row 0..127 within half */               \
    int cb_  = ((c_ & 7) << 4) ^ ((r_ & 7) << 4);                                         \
    gl_lds16((src) + (size_t)((rowbase) + r_) * K + (kt_) + (cb_ >> 1),                   \
             &SH[(base_u16) + cb0_ * 8]);                                                 \
  }                                                                                       \
} while(0)

__global__ __launch_bounds__(512, 1) void gemm_qkv256_k(
    const u16* __restrict__ A, const u16* __restrict__ Bt,
    u16* __restrict__ qk, u16* __restrict__ vt,
    const float2* __restrict__ rtab, int K)
{
  __shared__ __align__(16) u16 SH[65536];   // 128KB
  const int tid = threadIdx.x, lane = tid & 63, wv = tid >> 6;
  const int wsr = wv >> 2, wsc = wv & 3;     // 2(M) x 4(N) wave grid
  const int m0 = blockIdx.y * 256, n0 = blockIdx.x * 256;
  const int rq = lane >> 4, cl = lane & 15;
  const int NT = K >> 6;                     // 32

  const f32x4 Z = {0.f, 0.f, 0.f, 0.f};
  f32x4 acc[2][2][4][2];                     // [i][j][mf][nf]
  #pragma unroll
  for (int i = 0; i < 2; i++)
    #pragma unroll
    for (int j = 0; j < 2; j++)
      #pragma unroll
      for (int mf = 0; mf < 4; mf++)
        #pragma unroll
        for (int nf = 0; nf < 2; nf++) acc[i][j][mf][nf] = Z;

  // prologue stages (order matters for vmcnt ledger):
  STG_HALF(0,                 A,  m0 + 0,   0);    // A0(0)
  STG_HALF(32768,             Bt, n0 + 0,   0);    // B0(0)
  STG_HALF(8192,              A,  m0 + 128, 0);    // A1(0)
  STG_HALF(32768 + 8192,      Bt, n0 + 128, 0);    // B1(0)
  STG_HALF(16384,             A,  m0 + 0,   64);   // A0(1)
  STG_HALF(32768 + 16384,     Bt, n0 + 0,   64);   // B0(1)

  for (int t = 0; t < NT; t++){
    const int X = t & 1;
    const char* Ab = (const char*)SH + X * 32768;
    const char* Bb = (const char*)SH + 65536 + X * 32768;
    bf16x8 af[4][2], bfb[2][2];

    // ---- ph0: quadrant (0,0) ----
    __builtin_amdgcn_sched_barrier(0);
    if (t == NT - 1) asm volatile("s_waitcnt vmcnt(0)" ::: "memory");
    else             asm volatile("s_waitcnt vmcnt(4)" ::: "memory");
    __builtin_amdgcn_sched_barrier(0);
    __builtin_amdgcn_s_barrier();
    __builtin_amdgcn_sched_barrier(0);
    #pragma unroll
    for (int mf = 0; mf < 4; mf++){
      int gr = wsr * 64 + mf * 16 + cl;                      // i=0
      #pragma unroll
      for (int ks = 0; ks < 2; ks++)
        af[mf][ks] = *(const bf16x8*)(Ab + gr * 128 + ((ks * 64 + rq * 16) ^ ((gr & 7) << 4)));
    }
    #pragma unroll
    for (int nf = 0; nf < 2; nf++){
      int gc = wsc * 32 + nf * 16 + cl;                      // j=0
      #pragma unroll
      for (int ks = 0; ks < 2; ks++)
        bfb[nf][ks] = *(const bf16x8*)(Bb + gc * 128 + ((ks * 64 + rq * 16) ^ ((gc & 7) << 4)));
    }
    if (t + 1 < NT) STG_HALF(((t + 1) & 1) * 16384 + 8192, A, m0 + 128, (t + 1) * 64);   // A1(t+1)
    __builtin_amdgcn_sched_barrier(0);
    asm volatile("s_waitcnt lgkmcnt(0)" ::: "memory");
    __builtin_amdgcn_sched_barrier(0);
    __builtin_amdgcn_s_setprio(1);
    #pragma unroll
    for (int mf = 0; mf < 4; mf++)
      #pragma unroll
      for (int nf = 0; nf < 2; nf++)
        #pragma unroll
        for (int ks = 0; ks < 2; ks++)
          acc[0][0][mf][nf] = __builtin_amdgcn_mfma_f32_16x16x32_bf16(af[mf][ks], bfb[nf][ks], acc[0][0][mf][nf], 0, 0, 0);
    __builtin_amdgcn_s_setprio(0);
    __builtin_amdgcn_sched_barrier(0);

    // ---- ph1: quadrant (0,1), reuse af ----
    __builtin_amdgcn_s_barrier();
    __builtin_amdgcn_sched_barrier(0);
    #pragma unroll
    for (int nf = 0; nf < 2; nf++){
      int gc = 128 + wsc * 32 + nf * 16 + cl;                // j=1
      #pragma unroll
      for (int ks = 0; ks < 2; ks++)
        bfb[nf][ks] = *(const bf16x8*)(Bb + gc * 128 + ((ks * 64 + rq * 16) ^ ((gc & 7) << 4)));
    }
    if (t + 1 < NT) STG_HALF(32768 + ((t + 1) & 1) * 16384 + 8192, Bt, n0 + 128, (t + 1) * 64); // B1(t+1)
    __builtin_amdgcn_sched_barrier(0);
    asm volatile("s_waitcnt lgkmcnt(0)" ::: "memory");
    __builtin_amdgcn_sched_barrier(0);
    __builtin_amdgcn_s_setprio(1);
    #pragma unroll
    for (int mf = 0; mf < 4; mf++)
      #pragma unroll
      for (int nf = 0; nf < 2; nf++)
        #pragma unroll
        for (int ks = 0; ks < 2; ks++)
          acc[0][1][mf][nf] = __builtin_amdgcn_mfma_f32_16x16x32_bf16(af[mf][ks], bfb[nf][ks], acc[0][1][mf][nf], 0, 0, 0);
    __builtin_amdgcn_s_setprio(0);
    __builtin_amdgcn_sched_barrier(0);

    // ---- ph2: quadrant (1,0) ----
    __builtin_amdgcn_s_barrier();
    __builtin_amdgcn_sched_barrier(0);
    #pragma unroll
    for (int mf = 0; mf < 4; mf++){
      int gr = 128 + wsr * 64 + mf * 16 + cl;                // i=1
      #pragma unroll
      for (int ks = 0; ks < 2; ks++)
        af[mf][ks] = *(const bf16x8*)(Ab + gr * 128 + ((ks * 64 + rq * 16) ^ ((gr & 7) << 4)));
    }
    #pragma unroll
    for (int nf = 0; nf < 2; nf++){
      int gc = wsc * 32 + nf * 16 + cl;                      // j=0 (re-read)
      #pragma unroll
      for (int ks = 0; ks < 2; ks++)
        bfb[nf][ks] = *(const bf16x8*)(Bb + gc * 128 + ((ks * 64 + rq * 16) ^ ((gc & 7) << 4)));
    }
    if (t + 2 < NT) STG_HALF((t & 1) * 16384, A, m0 + 0, (t + 2) * 64);                  // A0(t+2)
    __builtin_amdgcn_sched_barrier(0);
    asm volatile("s_waitcnt lgkmcnt(0)" ::: "memory");
    __builtin_amdgcn_sched_barrier(0);
    __builtin_amdgcn_s_setprio(1);
    #pragma unroll
    for (int mf = 0; mf < 4; mf++)
      #pragma unroll
      for (int nf = 0; nf < 2; nf++)
        #pragma unroll
        for (int ks = 0; ks < 2; ks++)
          acc[1][0][mf][nf] = __builtin_amdgcn_mfma_f32_16x16x32_bf16(af[mf][ks], bfb[nf][ks], acc[1][0][mf][nf], 0, 0, 0);
    __builtin_amdgcn_s_setprio(0);
    __builtin_amdgcn_sched_barrier(0);

    // ---- ph3: quadrant (1,1), reuse af ----
    __builtin_amdgcn_s_barrier();
    __builtin_amdgcn_sched_barrier(0);
    #pragma unroll
    for (int nf = 0; nf < 2; nf++){
      int gc = 128 + wsc * 32 + nf * 16 + cl;                // j=1
      #pragma unroll
      for (int ks = 0; ks < 2; ks++)
        bfb[nf][ks] = *(const bf16x8*)(Bb + gc * 128 + ((ks * 64 + rq * 16) ^ ((gc & 7) << 4)));
    }
    if (t + 2 < NT) STG_HALF(32768 + (t & 1) * 16384, Bt, n0 + 0, (t + 2) * 64);         // B0(t+2)
    __builtin_amdgcn_sched_barrier(0);
    asm volatile("s_waitcnt lgkmcnt(0)" ::: "memory");
    __builtin_amdgcn_sched_barrier(0);
    __builtin_amdgcn_s_setprio(1);
    #pragma unroll
    for (int mf = 0; mf < 4; mf++)
      #pragma unroll
      for (int nf = 0; nf < 2; nf++)
        #pragma unroll
        for (int ks = 0; ks < 2; ks++)
          acc[1][1][mf][nf] = __builtin_amdgcn_mfma_f32_16x16x32_bf16(af[mf][ks], bfb[nf][ks], acc[1][1][mf][nf], 0, 0, 0);
    __builtin_amdgcn_s_setprio(0);
    __builtin_amdgcn_sched_barrier(0);
  }

  // ---- fused epilogue: two row-half passes over the 256x256 tile ----
  const int sec = n0 >> 11;       // 0=q, 1=k, 2=v
  const int hd2 = n0 >> 7;        // first head-col of this tile (even)
  u16* ES = SH;

  #pragma unroll
  for (int ih = 0; ih < 2; ih++){
    __syncthreads();
    // stage this row-half's acc -> ES[128][EST2]
    #pragma unroll
    for (int j = 0; j < 2; j++)
      #pragma unroll
      for (int mf = 0; mf < 4; mf++){
        int er = wsr * 64 + mf * 16 + rq * 4;
        #pragma unroll
        for (int nf = 0; nf < 2; nf++){
          int ec = j * 128 + wsc * 32 + nf * 16 + cl;
          #pragma unroll
          for (int rr = 0; rr < 4; rr++)
            ES[(er + rr) * EST2 + ec] = f2bf(acc[ih][j][mf][nf][rr]);
        }
      }
    __syncthreads();

    if (sec < 2){
      // rope: thread -> row r, head j, d-segment dbase
      const float fsc = (sec == 0) ? 0.12753375f : 1.0f;  // q: 1/sqrt(128)*log2e
      const int r = tid >> 2, cq = tid & 3;
      const int j = cq >> 1, dbase = (cq & 1) * 32;
      const int grow = m0 + ih * 128 + r;
      const int l = grow & (LL - 1);
      const float2* tab = rtab + l * 64 + dbase;
      const u16* srow = &ES[r * EST2 + j * 128];
      u16* orow = qk + (size_t)grow * QKN + n0 + j * 128;
      #pragma unroll
      for (int g = 0; g < 4; g++){
        bf16x8 x1v = *(const bf16x8*)(srow + dbase + g * 8);
        bf16x8 x2v = *(const bf16x8*)(srow + dbase + 64 + g * 8);
        bf16x8 o1, o2;
        #pragma unroll
        for (int i8 = 0; i8 < 8; i8++){
          float2 cs = tab[g * 8 + i8];
          float x1 = (float)x1v[i8], x2 = (float)x2v[i8];
          o1[i8] = (__bf16)((x1 * cs.x - x2 * cs.y) * fsc);
          o2[i8] = (__bf16)((x1 * cs.y + x2 * cs.x) * fsc);
        }
        *(bf16x8*)(orow + dbase + g * 8)      = o1;
        *(bf16x8*)(orow + dbase + 64 + g * 8) = o2;
      }
    } else {
      // v: thread -> column c (head j, dim d), l-half lh; write vt[bh][d][l]
      const int c = tid >> 1, lh = tid & 1;
      const int j = c >> 7, d = c & 127;
      const int grow0 = m0 + ih * 128;
      const int bh = ((grow0 >> 11) << 4) + (hd2 - 32 + j);
      u16* vrow = vt + ((size_t)bh * HDD + d) * LL + (grow0 & (LL - 1)) + lh * 64;
      #pragma unroll
      for (int g = 0; g < 8; g++){
        bf16x8 o;
        #pragma unroll
        for (int i8 = 0; i8 < 8; i8++)
          o[i8] = *(__bf16*)&ES[(lh * 64 + g * 8 + i8) * EST2 + c];
        *(bf16x8*)(vrow + g * 8) = o;
      }
    }
  }
}

// ---------------- GEMM 128x256 counted-vmcnt (proven for gemm2) ----------------

#define G2_STAGE(kt, bsel) do {                                                           \
  _Pragma("unroll")                                                                       \
  for (int i_ = 0; i_ < 2; i_++){     /* A: 128x64 = 1024 chunks */                       \
    int c_ = ((i_ * 8 + wv) * 64) + lane;                                                 \
    int p_ = c_ * 16;                                                                     \
    int r_ = p_ >> 7; int cb_ = (p_ & 127) ^ ((r_ & 7) << 4);                             \
    gl_lds16(A + (size_t)(m0 + r_) * K + (kt) + (cb_ >> 1),                               \
             &AB[bsel][((i_ * 8 + wv) * 64) * 8]);                                        \
  }                                                                                       \
  _Pragma("unroll")                                                                       \
  for (int i_ = 0; i_ < 4; i_++){     /* B: 256x64 = 2048 chunks */                       \
    int c_ = ((i_ * 8 + wv) * 64) + lane;                                                 \
    int p_ = c_ * 16;                                                                     \
    int r_ = p_ >> 7; int cb_ = (p_ & 127) ^ ((r_ & 7) << 4);                             \
    gl_lds16(Bt + (size_t)(n0 + r_) * K + (kt) + (cb_ >> 1),                              \
             &AB[bsel][8192 + ((i_ * 8 + wv) * 64) * 8]);                                 \
  }                                                                                       \
} while(0)

template<int OUT_BF16>
__global__ __launch_bounds__(512, 1) void gemm_bt2_k(
    const u16* __restrict__ A, const u16* __restrict__ Bt,
    void* __restrict__ Cout, int M, int N, int K)
{
  __shared__ __align__(16) u16 AB[2][24576];   // per buf: A[128][64] @0, B[256][64] @8192
  const int tid = threadIdx.x, lane = tid & 63, wv = tid >> 6;
  const int wr = wv >> 2, wc = wv & 3;          // 2 (M) x 4 (N) waves
  const int m0 = blockIdx.y * 128, n0 = blockIdx.x * 256;
  const int rq = lane >> 4, cl = lane & 15;
  const int NT = K >> 6;                        // 64-wide K tiles

  const f32x4 Z = {0.f, 0.f, 0.f, 0.f};
  f32x4 acc[4][4];
  #pragma unroll
  for (int m = 0; m < 4; m++)
    #pragma unroll
    for (int n = 0; n < 4; n++) acc[m][n] = Z;

  G2_STAGE(0, 0);
  G2_STAGE(64, 1);
  asm volatile("s_waitcnt vmcnt(6)");
  __builtin_amdgcn_sched_barrier(0);
  __builtin_amdgcn_s_barrier();

  int cur = 0;
  for (int t = 0; t < NT; t++){
    const char* As_ = (const char*)&AB[cur][0];
    const char* Bs_ = (const char*)&AB[cur][8192];

    #pragma unroll
    for (int ks = 0; ks < 2; ks++){
      const int kb = ks * 64 + rq * 16;
      bf16x8 a[4], b[4];
      #pragma unroll
      for (int m = 0; m < 4; m++){
        int r = wr * 64 + m * 16 + cl;
        a[m] = *(const bf16x8*)(As_ + r * 128 + (kb ^ ((r & 7) << 4)));
      }
      #pragma unroll
      for (int n = 0; n < 4; n++){
        int r = wc * 64 + n * 16 + cl;
        b[n] = *(const bf16x8*)(Bs_ + r * 128 + (kb ^ ((r & 7) << 4)));
      }
      __builtin_amdgcn_s_setprio(1);
      #pragma unroll
      for (int m = 0; m < 4; m++)
        #pragma unroll
        for (int n = 0; n < 4; n++)
          acc[m][n] = __builtin_amdgcn_mfma_f32_16x16x32_bf16(a[m], b[n], acc[m][n], 0, 0, 0);
      __builtin_amdgcn_s_setprio(0);
    }

    __builtin_amdgcn_sched_barrier(0);
    __builtin_amdgcn_s_barrier();              // every wave done READING buf[cur]

    if (t + 2 < NT){
      G2_STAGE((t + 2) * 64, cur);             // overwrite freed buffer
      asm volatile("s_waitcnt vmcnt(6)");      // tile t+1 landed; t+2 stays in flight
    } else {
      asm volatile("s_waitcnt vmcnt(0)");      // tail: drain remaining
    }
    __builtin_amdgcn_sched_barrier(0);
    __builtin_amdgcn_s_barrier();              // every wave's tile t+1 landed
    cur ^= 1;
  }

  #pragma unroll
  for (int m = 0; m < 4; m++){
    int gr0 = m0 + wr * 64 + m * 16 + rq * 4;
    #pragma unroll
    for (int n = 0; n < 4; n++){
      int gc = n0 + wc * 64 + n * 16 + cl;
      #pragma unroll
      for (int rr = 0; rr < 4; rr++){
        if (OUT_BF16) ((u16*)Cout)[(size_t)(gr0 + rr) * N + gc] = f2bf(acc[m][n][rr]);
        else          ((float*)Cout)[(size_t)(gr0 + rr) * N + gc] = acc[m][n][rr];
      }
    }
  }
}

// ---------------- flash attention v7: counted-vmcnt + 3 blocks/CU ----------
// grid (bh=32 fast, pair p=0..15), 256 thr = 4 waves x 16 q-rows.
// LDS 48KB: K dbuf 2x16KB + V single 16KB; P overlays the consumed K buffer
// -> 3 blocks/CU (12 waves). Per iter: issue V(j) then K(j+1) -> vmcnt(4)
// (K(j)+V(j) landed, K(j+1) flying) -> bar -> QK -> bar (K-reads done) ->
// softmax/P into Kb[cur] -> PV -> bar (V+P reads done). 3 barriers, 1 wait.

#define STAGE_K(jj, bsel) do {                                                            \
  _Pragma("unroll")                                                                       \
  for (int i_ = 0; i_ < 4; i_++){                                                         \
    int fb_ = (i_ * 4 + wv) * 64;                                                         \
    int p_  = (fb_ + lane) * 16;                                                          \
    int r_ = p_ >> 8; int cb_ = (p_ & 255) ^ ((r_ & 7) << 4);                             \
    gl_lds16(qk + (size_t)(b * LL + (jj) * 64 + r_) * QKN + 2048 + h * HDD + (cb_ >> 1),  \
             &Kb[bsel][fb_ * 8]);                                                         \
  }                                                                                       \
} while(0)

#define STAGE_V(jj) do {                                                                  \
  _Pragma("unroll")                                                                       \
  for (int i_ = 0; i_ < 4; i_++){                                                         \
    int fb_ = (i_ * 4 + wv) * 64;                                                         \
    int p_  = (fb_ + lane) * 16;                                                          \
    int r_ = p_ >> 7; int cb_ = (p_ & 127) ^ ((r_ & 7) << 4);                             \
    gl_lds16(vt + (size_t)(bh * HDD + r_) * LL + (jj) * 64 + (cb_ >> 1), &Vs[fb_ * 8]);   \
  }                                                                                       \
} while(0)

__global__ __launch_bounds__(256, 3) void attn_k(
    const u16* __restrict__ qk, const u16* __restrict__ vt,
    u16* __restrict__ aout)
{
  __shared__ __align__(16) u16 Kb[2][64 * 128];   // K tiles, 2x16KB
  __shared__ __align__(16) u16 Vs[128 * 64];      // V^T tile, 16KB (single)
  const int tid = threadIdx.x, lane = tid & 63, wv = tid >> 6;
  const int bh = blockIdx.x;                      // fast dim -> XCD = bh % 8
  const int pr = blockIdx.y;                      // pair index 0..15
  const int b = bh >> 4, h = bh & 15;
  const int rq = lane >> 4, cl = lane & 15;

  bf16x8 ones;
  #pragma unroll
  for (int i = 0; i < 8; i++) ones[i] = (__bf16)1.0f;
  const f32x4 Z = {0.f, 0.f, 0.f, 0.f};

  int cur = 0;
  STAGE_K(0, 0);                                  // phase-A tile 0 (only K prologued)

  #pragma unroll
  for (int ph = 0; ph < 2; ph++){
    const int qt = ph ? pr : (31 - pr);           // 64-row q-tile index
    const int nj = qt + 1;

    bf16x8 qf[4];
    {
      const u16* qb = qk + (size_t)(b * LL + qt * 64 + wv * 16 + cl) * QKN + h * HDD + rq * 8;
      #pragma unroll
      for (int ks = 0; ks < 4; ks++) qf[ks] = *(const bf16x8*)(qb + ks * 32);
    }

    f32x4 acco[8], accl;
    float mst[4];
    #pragma unroll
    for (int n = 0; n < 8; n++) acco[n] = Z;
    accl = Z;
    #pragma unroll
    for (int rr = 0; rr < 4; rr++) mst[rr] = -INFINITY;

    for (int j = 0; j < nj; j++){
      const bool sn = (j + 1 < nj) || (ph == 0);  // stages a next-K this iter
      STAGE_V(j);                                  // V(j): older in vm queue
      if (j + 1 < nj)      STAGE_K(j + 1, cur ^ 1);
      else if (ph == 0)    STAGE_K(0,     cur ^ 1);  // cross into phase B
      __builtin_amdgcn_sched_barrier(0);
      if (sn) asm volatile("s_waitcnt vmcnt(4)" ::: "memory");  // K(j)+V(j) landed
      else    asm volatile("s_waitcnt vmcnt(0)" ::: "memory");
      __builtin_amdgcn_sched_barrier(0);
      __builtin_amdgcn_s_barrier();               // all waves' K(j),V(j) landed
      __builtin_amdgcn_sched_barrier(0);

      // S = Q K^T (16 q-rows x 64 kv per wave)
      f32x4 sv[4];
      {
        const char* KsC = (const char*)&Kb[cur][0];
        #pragma unroll
        for (int ct = 0; ct < 4; ct++) sv[ct] = Z;
        #pragma unroll
        for (int ks = 0; ks < 4; ks++){
          const int kb = ks * 64 + rq * 16;
          #pragma unroll
          for (int ct = 0; ct < 4; ct++){
            int r = ct * 16 + cl;
            bf16x8 bfr = *(const bf16x8*)(KsC + r * 256 + (kb ^ ((r & 7) << 4)));
            sv[ct] = __builtin_amdgcn_mfma_f32_16x16x32_bf16(qf[ks], bfr, sv[ct], 0, 0, 0);
          }
        }
      }

      __builtin_amdgcn_sched_barrier(0);
      __builtin_amdgcn_s_barrier();               // all waves done READING Kb[cur]
      __builtin_amdgcn_sched_barrier(0);

      // softmax (exp2 domain) + P overlays consumed Kb[cur] (per-wave 2KB slot)
      {
        char* pbase = (char*)&Kb[cur][0] + wv * 2048;
        const bool msk = (j == qt);                 // diagonal tile only

        float p4[4][4], lmx[4];
        #pragma unroll
        for (int rr = 0; rr < 4; rr++) lmx[rr] = -1e30f;
        const int qg = qt * 64 + wv * 16 + rq * 4;
        #pragma unroll
        for (int ct = 0; ct < 4; ct++){
          int col = j * 64 + ct * 16 + cl;
          #pragma unroll
          for (int rr = 0; rr < 4; rr++){
            float v = sv[ct][rr];                   // already log2-domain
            if (msk && col > qg + rr) v = -1e30f;
            p4[ct][rr] = v;
            lmx[rr] = fmaxf(lmx[rr], v);
          }
        }
        float need = -1e30f;
        #pragma unroll
        for (int rr = 0; rr < 4; rr++) need = fmaxf(need, lmx[rr] - mst[rr]);
        if (__any(need > THR2)){
          float mx[4];
          #pragma unroll
          for (int rr = 0; rr < 4; rr++) mx[rr] = lmx[rr];
          #pragma unroll
          for (int off = 1; off < 16; off <<= 1)
            #pragma unroll
            for (int rr = 0; rr < 4; rr++)
              mx[rr] = fmaxf(mx[rr], __shfl_xor(mx[rr], off, 64));
          #pragma unroll
          for (int rr = 0; rr < 4; rr++){
            float mn  = fmaxf(mst[rr], mx[rr]);
            float fsc = exp2_fast(mst[rr] - mn);
            mst[rr] = mn;
            accl[rr] *= fsc;
            #pragma unroll
            for (int n = 0; n < 8; n++) acco[n][rr] *= fsc;
          }
        }
        #pragma unroll
        for (int ct = 0; ct < 4; ct++)
          #pragma unroll
          for (int rr = 0; rr < 4; rr++){
            float e = exp2_fast(p4[ct][rr] - mst[rr]);
            int wr = rq * 4 + rr;
            *(u16*)(pbase + wr * 128 + (((ct * 16 + cl) * 2) ^ ((wr & 7) << 4))) = f2bf(e);
          }

        // O += P V ; l += P 1  (V resident; P in-wave RAW via own slot)
        const char* VsC = (const char*)Vs;
        #pragma unroll
        for (int ks = 0; ks < 2; ks++){
          const int kvb = ks * 64 + rq * 16;
          bf16x8 pa = *(const bf16x8*)(pbase + cl * 128 + (kvb ^ ((cl & 7) << 4)));
          accl = __builtin_amdgcn_mfma_f32_16x16x32_bf16(pa, ones, accl, 0, 0, 0);
          #pragma unroll
          for (int n = 0; n < 8; n++){
            int r = n * 16 + cl;
            bf16x8 bfr = *(const bf16x8*)(VsC + r * 128 + (kvb ^ ((r & 7) << 4)));
            acco[n] = __builtin_amdgcn_mfma_f32_16x16x32_bf16(pa, bfr, acco[n], 0, 0, 0);
          }
        }
      }

      __builtin_amdgcn_sched_barrier(0);
      __builtin_amdgcn_s_barrier();               // Vs + P reads done before next staging
      __builtin_amdgcn_sched_barrier(0);
      cur ^= 1;
    }

    // direct write-out
    #pragma unroll
    for (int rr = 0; rr < 4; rr++){
      float inv = 1.0f / accl[rr];
      size_t grow = (size_t)(b * LL + qt * 64 + wv * 16 + rq * 4 + rr);
      #pragma unroll
      for (int n = 0; n < 8; n++)
        aout[grow * HIDD + h * HDD + n * 16 + cl] = f2bf(acco[n][rr] * inv);
    }
  }
}

// ---------------- launcher ----------------

extern "C" void kernel_launch(void* const* d_in, const int* in_sizes, int n_in,
                              void* d_out, int out_size, void* d_ws, size_t ws_size,
                              hipStream_t stream)
{
  const float* x  = (const float*)d_in[0];
  // d_in[1] = mask (causal; applied analytically)
  const float* Wq = (const float*)d_in[2];
  const float* Wk = (const float*)d_in[3];
  const float* Wv = (const float*)d_in[4];
  const float* Wo = (const float*)d_in[5];
  float* out = (float*)d_out;

  if (ws_size < 120586240ull) return;  // need ~115 MB of scratch

  char* ws = (char*)d_ws;
  u16*    xb   = (u16*)(ws);                   // 4096x2048 bf16   (16 MB)
  u16*    Wt   = (u16*)(ws + 16777216ull);     // 6144x2048 bf16   (24 MB) = [Wq|Wk|Wv]^T
  u16*    Wot  = (u16*)(ws + 41943040ull);     // 2048x2048 bf16   ( 8 MB)
  u16*    qk   = (u16*)(ws + 50331648ull);     // 4096x4096 bf16   (32 MB) roped q|k
  u16*    vt   = (u16*)(ws + 83886080ull);     // 32x128x2048 bf16 (16 MB)
  u16*    aout = (u16*)(ws + 100663296ull);    // 4096x2048 bf16   (16 MB)
  float2* rtab = (float2*)(ws + 117440512ull); // 2048x64 float2   ( 1 MB)

  cvt_f32_bf16_k<<<2097152 / 256, 256, 0, stream>>>(x, xb, 2097152);
  rope_table_k<<<131072 / 256, 256, 0, stream>>>(rtab);
  transpose_cvt4_k<<<dim3(32, 32, 4), 256, 0, stream>>>(Wq, Wk, Wv, Wo, Wt, Wot);

  gemm_qkv256_k<<<dim3(6144 / 256, 4096 / 256), 512, 0, stream>>>(xb, Wt, qk, vt, rtab, 2048);

  attn_k<<<dim3(32, 16), 256, 0, stream>>>(qk, vt, aout);

  gemm_bt2_k<0><<<dim3(2048 / 256, 4096 / 128), 512, 0, stream>>>(aout, Wot, out, 4096, 2048, 2048);
}

// Round 22
// 256.286 us; speedup vs baseline: 1.0266x; 1.0266x over previous
//
#include <hip/hip_runtime.h>
#include <math.h>

#define BB   2
#define LL   2048
#define HIDD 2048
#define NHH  16
#define HDD  128
#define QKN  4096   // q|k buffer row stride
#define THR2 11.5416f  // defer-max threshold, log2 domain (= 8 nats)
#define EST2 264    // 256-wide epilogue LDS row stride (u16): 528B rows, 16B-aligned

typedef unsigned short u16;
typedef float  f32x4 __attribute__((ext_vector_type(4)));
typedef __bf16 bf16x8 __attribute__((ext_vector_type(8)));

static __device__ __forceinline__ float exp2_fast(float x){
  return __builtin_amdgcn_exp2f(x);    // v_exp_f32 (native 2^x)
}
static __device__ __forceinline__ u16 f2bf(float x){
  unsigned u = __float_as_uint(x);
  return (u16)((u + 0x7fffu + ((u >> 16) & 1u)) >> 16);
}
static __device__ __forceinline__ float bf2f(u16 b){
  return __uint_as_float(((unsigned)b) << 16);
}
static __device__ __forceinline__ void gl_lds16(const void* g, void* l){
  __builtin_amdgcn_global_load_lds(
      (__attribute__((address_space(1))) void*)(void*)g,
      (__attribute__((address_space(3))) void*)l,
      16, 0, 0);
}

// ---------------- prep kernels ----------------

__global__ void cvt_f32_bf16_k(const float* __restrict__ src, u16* __restrict__ dst, int n4){
  int i = blockIdx.x * blockDim.x + threadIdx.x;
  if (i >= n4) return;
  float4 v = ((const float4*)src)[i];
  ushort4 o;
  o.x = f2bf(v.x); o.y = f2bf(v.y); o.z = f2bf(v.z); o.w = f2bf(v.w);
  ((ushort4*)dst)[i] = o;
}

// cos/sin table: tab[l*64+d] = (cos(th), sin(th)), th = (l/4)*exp(-d*ln(1e5)/64)
__global__ void rope_table_k(float2* __restrict__ tab){
  int idx = blockIdx.x * blockDim.x + threadIdx.x;   // 2048*64
  int l = idx >> 6, d = idx & 63;
  float fr = __expf(-(float)d * 0.17988946f);
  float th = (float)l * 0.25f * fr;
  float s, c;
  sincosf(th, &s, &c);
  tab[idx] = make_float2(c, s);
}

// fused 4x (2048^2 f32 -> transposed bf16). grid (32,32,4), 256 thr, 64x64 tiles.
__global__ __launch_bounds__(256) void transpose_cvt4_k(
    const float* __restrict__ Wq, const float* __restrict__ Wk,
    const float* __restrict__ Wv, const float* __restrict__ Wo,
    u16* __restrict__ Wt, u16* __restrict__ Wot)
{
  __shared__ u16 t[64][66];
  const int z = blockIdx.z;
  const float* src = (z == 0) ? Wq : (z == 1) ? Wk : (z == 2) ? Wv : Wo;
  u16* dst = (z == 3) ? Wot : (Wt + (size_t)z * 2048 * 2048);
  const int c0 = blockIdx.x * 64, r0 = blockIdx.y * 64;
  const int tid = threadIdx.x;

  #pragma unroll
  for (int i = 0; i < 4; i++){
    int r  = i * 16 + (tid >> 4);
    int c4 = (tid & 15) * 4;
    float4 v = *(const float4*)&src[(size_t)(r0 + r) * 2048 + c0 + c4];
    t[c4 + 0][r] = f2bf(v.x);
    t[c4 + 1][r] = f2bf(v.y);
    t[c4 + 2][r] = f2bf(v.z);
    t[c4 + 3][r] = f2bf(v.w);
  }
  __syncthreads();
  #pragma unroll
  for (int i = 0; i < 2; i++){
    int c  = i * 32 + (tid >> 3);
    int rs = (tid & 7) * 8;
    const unsigned* p = (const unsigned*)&t[c][rs];   // 4B-aligned
    unsigned w0 = p[0], w1 = p[1], w2 = p[2], w3 = p[3];
    u16* d = &dst[(size_t)(c0 + c) * 2048 + r0 + rs];
    ((unsigned*)d)[0] = w0; ((unsigned*)d)[1] = w1;
    ((unsigned*)d)[2] = w2; ((unsigned*)d)[3] = w3;
  }
}

// ---------------- GEMM1: 256x256 tile, 4-phase quadrant schedule, fused epilogue ------
// (champion, r17/r20). 8 waves (2M x 4N). Per phase: block C-quadrant (i,j) 128x128;
// all waves read A-half i + B-half j. Stage ledger: ph0: A1(t+1), ph1: B1(t+1),
// ph2: A0(t+2), ph3: B0(t+2). Boundary wait vmcnt(4); vmcnt(0) last tile.
// LDS map (bytes): A bufs [0,65536), B bufs [65536,131072).

#define STG_HALF(base_u16, src, rowbase, kt_) do {                                        \
  _Pragma("unroll")                                                                       \
  for (int i_ = 0; i_ < 2; i_++){                                                         \
    int cb0_ = i_ * 512 + wv * 64;             /* wave-uniform chunk base */              \
    int c_   = cb0_ + lane;                                                               \
    int r_   = c_ >> 3;                        /* row 0..127 within half */               \
    int cb_  = ((c_ & 7) << 4) ^ ((r_ & 7) << 4);                                         \
    gl_lds16((src) + (size_t)((rowbase) + r_) * K + (kt_) + (cb_ >> 1),                   \
             &SH[(base_u16) + cb0_ * 8]);                                                 \
  }                                                                                       \
} while(0)

__global__ __launch_bounds__(512, 1) void gemm_qkv256_k(
    const u16* __restrict__ A, const u16* __restrict__ Bt,
    u16* __restrict__ qk, u16* __restrict__ vt,
    const float2* __restrict__ rtab, int K)
{
  __shared__ __align__(16) u16 SH[65536];   // 128KB
  const int tid = threadIdx.x, lane = tid & 63, wv = tid >> 6;
  const int wsr = wv >> 2, wsc = wv & 3;     // 2(M) x 4(N) wave grid
  const int m0 = blockIdx.y * 256, n0 = blockIdx.x * 256;
  const int rq = lane >> 4, cl = lane & 15;
  const int NT = K >> 6;                     // 32

  const f32x4 Z = {0.f, 0.f, 0.f, 0.f};
  f32x4 acc[2][2][4][2];                     // [i][j][mf][nf]
  #pragma unroll
  for (int i = 0; i < 2; i++)
    #pragma unroll
    for (int j = 0; j < 2; j++)
      #pragma unroll
      for (int mf = 0; mf < 4; mf++)
        #pragma unroll
        for (int nf = 0; nf < 2; nf++) acc[i][j][mf][nf] = Z;

  // prologue stages (order matters for vmcnt ledger):
  STG_HALF(0,                 A,  m0 + 0,   0);    // A0(0)
  STG_HALF(32768,             Bt, n0 + 0,   0);    // B0(0)
  STG_HALF(8192,              A,  m0 + 128, 0);    // A1(0)
  STG_HALF(32768 + 8192,      Bt, n0 + 128, 0);    // B1(0)
  STG_HALF(16384,             A,  m0 + 0,   64);   // A0(1)
  STG_HALF(32768 + 16384,     Bt, n0 + 0,   64);   // B0(1)

  for (int t = 0; t < NT; t++){
    const int X = t & 1;
    const char* Ab = (const char*)SH + X * 32768;
    const char* Bb = (const char*)SH + 65536 + X * 32768;
    bf16x8 af[4][2], bfb[2][2];

    // ---- ph0: quadrant (0,0) ----
    __builtin_amdgcn_sched_barrier(0);
    if (t == NT - 1) asm volatile("s_waitcnt vmcnt(0)" ::: "memory");
    else             asm volatile("s_waitcnt vmcnt(4)" ::: "memory");
    __builtin_amdgcn_sched_barrier(0);
    __builtin_amdgcn_s_barrier();
    __builtin_amdgcn_sched_barrier(0);
    #pragma unroll
    for (int mf = 0; mf < 4; mf++){
      int gr = wsr * 64 + mf * 16 + cl;                      // i=0
      #pragma unroll
      for (int ks = 0; ks < 2; ks++)
        af[mf][ks] = *(const bf16x8*)(Ab + gr * 128 + ((ks * 64 + rq * 16) ^ ((gr & 7) << 4)));
    }
    #pragma unroll
    for (int nf = 0; nf < 2; nf++){
      int gc = wsc * 32 + nf * 16 + cl;                      // j=0
      #pragma unroll
      for (int ks = 0; ks < 2; ks++)
        bfb[nf][ks] = *(const bf16x8*)(Bb + gc * 128 + ((ks * 64 + rq * 16) ^ ((gc & 7) << 4)));
    }
    if (t + 1 < NT) STG_HALF(((t + 1) & 1) * 16384 + 8192, A, m0 + 128, (t + 1) * 64);   // A1(t+1)
    __builtin_amdgcn_sched_barrier(0);
    asm volatile("s_waitcnt lgkmcnt(0)" ::: "memory");
    __builtin_amdgcn_sched_barrier(0);
    __builtin_amdgcn_s_setprio(1);
    #pragma unroll
    for (int mf = 0; mf < 4; mf++)
      #pragma unroll
      for (int nf = 0; nf < 2; nf++)
        #pragma unroll
        for (int ks = 0; ks < 2; ks++)
          acc[0][0][mf][nf] = __builtin_amdgcn_mfma_f32_16x16x32_bf16(af[mf][ks], bfb[nf][ks], acc[0][0][mf][nf], 0, 0, 0);
    __builtin_amdgcn_s_setprio(0);
    __builtin_amdgcn_sched_barrier(0);

    // ---- ph1: quadrant (0,1), reuse af ----
    __builtin_amdgcn_s_barrier();
    __builtin_amdgcn_sched_barrier(0);
    #pragma unroll
    for (int nf = 0; nf < 2; nf++){
      int gc = 128 + wsc * 32 + nf * 16 + cl;                // j=1
      #pragma unroll
      for (int ks = 0; ks < 2; ks++)
        bfb[nf][ks] = *(const bf16x8*)(Bb + gc * 128 + ((ks * 64 + rq * 16) ^ ((gc & 7) << 4)));
    }
    if (t + 1 < NT) STG_HALF(32768 + ((t + 1) & 1) * 16384 + 8192, Bt, n0 + 128, (t + 1) * 64); // B1(t+1)
    __builtin_amdgcn_sched_barrier(0);
    asm volatile("s_waitcnt lgkmcnt(0)" ::: "memory");
    __builtin_amdgcn_sched_barrier(0);
    __builtin_amdgcn_s_setprio(1);
    #pragma unroll
    for (int mf = 0; mf < 4; mf++)
      #pragma unroll
      for (int nf = 0; nf < 2; nf++)
        #pragma unroll
        for (int ks = 0; ks < 2; ks++)
          acc[0][1][mf][nf] = __builtin_amdgcn_mfma_f32_16x16x32_bf16(af[mf][ks], bfb[nf][ks], acc[0][1][mf][nf], 0, 0, 0);
    __builtin_amdgcn_s_setprio(0);
    __builtin_amdgcn_sched_barrier(0);

    // ---- ph2: quadrant (1,0) ----
    __builtin_amdgcn_s_barrier();
    __builtin_amdgcn_sched_barrier(0);
    #pragma unroll
    for (int mf = 0; mf < 4; mf++){
      int gr = 128 + wsr * 64 + mf * 16 + cl;                // i=1
      #pragma unroll
      for (int ks = 0; ks < 2; ks++)
        af[mf][ks] = *(const bf16x8*)(Ab + gr * 128 + ((ks * 64 + rq * 16) ^ ((gr & 7) << 4)));
    }
    #pragma unroll
    for (int nf = 0; nf < 2; nf++){
      int gc = wsc * 32 + nf * 16 + cl;                      // j=0 (re-read)
      #pragma unroll
      for (int ks = 0; ks < 2; ks++)
        bfb[nf][ks] = *(const bf16x8*)(Bb + gc * 128 + ((ks * 64 + rq * 16) ^ ((gc & 7) << 4)));
    }
    if (t + 2 < NT) STG_HALF((t & 1) * 16384, A, m0 + 0, (t + 2) * 64);                  // A0(t+2)
    __builtin_amdgcn_sched_barrier(0);
    asm volatile("s_waitcnt lgkmcnt(0)" ::: "memory");
    __builtin_amdgcn_sched_barrier(0);
    __builtin_amdgcn_s_setprio(1);
    #pragma unroll
    for (int mf = 0; mf < 4; mf++)
      #pragma unroll
      for (int nf = 0; nf < 2; nf++)
        #pragma unroll
        for (int ks = 0; ks < 2; ks++)
          acc[1][0][mf][nf] = __builtin_amdgcn_mfma_f32_16x16x32_bf16(af[mf][ks], bfb[nf][ks], acc[1][0][mf][nf], 0, 0, 0);
    __builtin_amdgcn_s_setprio(0);
    __builtin_amdgcn_sched_barrier(0);

    // ---- ph3: quadrant (1,1), reuse af ----
    __builtin_amdgcn_s_barrier();
    __builtin_amdgcn_sched_barrier(0);
    #pragma unroll
    for (int nf = 0; nf < 2; nf++){
      int gc = 128 + wsc * 32 + nf * 16 + cl;                // j=1
      #pragma unroll
      for (int ks = 0; ks < 2; ks++)
        bfb[nf][ks] = *(const bf16x8*)(Bb + gc * 128 + ((ks * 64 + rq * 16) ^ ((gc & 7) << 4)));
    }
    if (t + 2 < NT) STG_HALF(32768 + (t & 1) * 16384, Bt, n0 + 0, (t + 2) * 64);         // B0(t+2)
    __builtin_amdgcn_sched_barrier(0);
    asm volatile("s_waitcnt lgkmcnt(0)" ::: "memory");
    __builtin_amdgcn_sched_barrier(0);
    __builtin_amdgcn_s_setprio(1);
    #pragma unroll
    for (int mf = 0; mf < 4; mf++)
      #pragma unroll
      for (int nf = 0; nf < 2; nf++)
        #pragma unroll
        for (int ks = 0; ks < 2; ks++)
          acc[1][1][mf][nf] = __builtin_amdgcn_mfma_f32_16x16x32_bf16(af[mf][ks], bfb[nf][ks], acc[1][1][mf][nf], 0, 0, 0);
    __builtin_amdgcn_s_setprio(0);
    __builtin_amdgcn_sched_barrier(0);
  }

  // ---- fused epilogue: two row-half passes over the 256x256 tile ----
  const int sec = n0 >> 11;       // 0=q, 1=k, 2=v
  const int hd2 = n0 >> 7;        // first head-col of this tile (even)
  u16* ES = SH;

  #pragma unroll
  for (int ih = 0; ih < 2; ih++){
    __syncthreads();
    // stage this row-half's acc -> ES[128][EST2]
    #pragma unroll
    for (int j = 0; j < 2; j++)
      #pragma unroll
      for (int mf = 0; mf < 4; mf++){
        int er = wsr * 64 + mf * 16 + rq * 4;
        #pragma unroll
        for (int nf = 0; nf < 2; nf++){
          int ec = j * 128 + wsc * 32 + nf * 16 + cl;
          #pragma unroll
          for (int rr = 0; rr < 4; rr++)
            ES[(er + rr) * EST2 + ec] = f2bf(acc[ih][j][mf][nf][rr]);
        }
      }
    __syncthreads();

    if (sec < 2){
      // rope: thread -> row r, head j, d-segment dbase
      const float fsc = (sec == 0) ? 0.12753375f : 1.0f;  // q: 1/sqrt(128)*log2e
      const int r = tid >> 2, cq = tid & 3;
      const int j = cq >> 1, dbase = (cq & 1) * 32;
      const int grow = m0 + ih * 128 + r;
      const int l = grow & (LL - 1);
      const float2* tab = rtab + l * 64 + dbase;
      const u16* srow = &ES[r * EST2 + j * 128];
      u16* orow = qk + (size_t)grow * QKN + n0 + j * 128;
      #pragma unroll
      for (int g = 0; g < 4; g++){
        bf16x8 x1v = *(const bf16x8*)(srow + dbase + g * 8);
        bf16x8 x2v = *(const bf16x8*)(srow + dbase + 64 + g * 8);
        bf16x8 o1, o2;
        #pragma unroll
        for (int i8 = 0; i8 < 8; i8++){
          float2 cs = tab[g * 8 + i8];
          float x1 = (float)x1v[i8], x2 = (float)x2v[i8];
          o1[i8] = (__bf16)((x1 * cs.x - x2 * cs.y) * fsc);
          o2[i8] = (__bf16)((x1 * cs.y + x2 * cs.x) * fsc);
        }
        *(bf16x8*)(orow + dbase + g * 8)      = o1;
        *(bf16x8*)(orow + dbase + 64 + g * 8) = o2;
      }
    } else {
      // v: thread -> column c (head j, dim d), l-half lh; write vt[bh][d][l]
      const int c = tid >> 1, lh = tid & 1;
      const int j = c >> 7, d = c & 127;
      const int grow0 = m0 + ih * 128;
      const int bh = ((grow0 >> 11) << 4) + (hd2 - 32 + j);
      u16* vrow = vt + ((size_t)bh * HDD + d) * LL + (grow0 & (LL - 1)) + lh * 64;
      #pragma unroll
      for (int g = 0; g < 8; g++){
        bf16x8 o;
        #pragma unroll
        for (int i8 = 0; i8 < 8; i8++)
          o[i8] = *(__bf16*)&ES[(lh * 64 + g * 8 + i8) * EST2 + c];
        *(bf16x8*)(vrow + g * 8) = o;
      }
    }
  }
}

// ---------------- GEMM 128x256 counted-vmcnt (proven for gemm2) ----------------

#define G2_STAGE(kt, bsel) do {                                                           \
  _Pragma("unroll")                                                                       \
  for (int i_ = 0; i_ < 2; i_++){     /* A: 128x64 = 1024 chunks */                       \
    int c_ = ((i_ * 8 + wv) * 64) + lane;                                                 \
    int p_ = c_ * 16;                                                                     \
    int r_ = p_ >> 7; int cb_ = (p_ & 127) ^ ((r_ & 7) << 4);                             \
    gl_lds16(A + (size_t)(m0 + r_) * K + (kt) + (cb_ >> 1),                               \
             &AB[bsel][((i_ * 8 + wv) * 64) * 8]);                                        \
  }                                                                                       \
  _Pragma("unroll")                                                                       \
  for (int i_ = 0; i_ < 4; i_++){     /* B: 256x64 = 2048 chunks */                       \
    int c_ = ((i_ * 8 + wv) * 64) + lane;                                                 \
    int p_ = c_ * 16;                                                                     \
    int r_ = p_ >> 7; int cb_ = (p_ & 127) ^ ((r_ & 7) << 4);                             \
    gl_lds16(Bt + (size_t)(n0 + r_) * K + (kt) + (cb_ >> 1),                              \
             &AB[bsel][8192 + ((i_ * 8 + wv) * 64) * 8]);                                 \
  }                                                                                       \
} while(0)

template<int OUT_BF16>
__global__ __launch_bounds__(512, 1) void gemm_bt2_k(
    const u16* __restrict__ A, const u16* __restrict__ Bt,
    void* __restrict__ Cout, int M, int N, int K)
{
  __shared__ __align__(16) u16 AB[2][24576];   // per buf: A[128][64] @0, B[256][64] @8192
  const int tid = threadIdx.x, lane = tid & 63, wv = tid >> 6;
  const int wr = wv >> 2, wc = wv & 3;          // 2 (M) x 4 (N) waves
  const int m0 = blockIdx.y * 128, n0 = blockIdx.x * 256;
  const int rq = lane >> 4, cl = lane & 15;
  const int NT = K >> 6;                        // 64-wide K tiles

  const f32x4 Z = {0.f, 0.f, 0.f, 0.f};
  f32x4 acc[4][4];
  #pragma unroll
  for (int m = 0; m < 4; m++)
    #pragma unroll
    for (int n = 0; n < 4; n++) acc[m][n] = Z;

  G2_STAGE(0, 0);
  G2_STAGE(64, 1);
  asm volatile("s_waitcnt vmcnt(6)");
  __builtin_amdgcn_sched_barrier(0);
  __builtin_amdgcn_s_barrier();

  int cur = 0;
  for (int t = 0; t < NT; t++){
    const char* As_ = (const char*)&AB[cur][0];
    const char* Bs_ = (const char*)&AB[cur][8192];

    #pragma unroll
    for (int ks = 0; ks < 2; ks++){
      const int kb = ks * 64 + rq * 16;
      bf16x8 a[4], b[4];
      #pragma unroll
      for (int m = 0; m < 4; m++){
        int r = wr * 64 + m * 16 + cl;
        a[m] = *(const bf16x8*)(As_ + r * 128 + (kb ^ ((r & 7) << 4)));
      }
      #pragma unroll
      for (int n = 0; n < 4; n++){
        int r = wc * 64 + n * 16 + cl;
        b[n] = *(const bf16x8*)(Bs_ + r * 128 + (kb ^ ((r & 7) << 4)));
      }
      __builtin_amdgcn_s_setprio(1);
      #pragma unroll
      for (int m = 0; m < 4; m++)
        #pragma unroll
        for (int n = 0; n < 4; n++)
          acc[m][n] = __builtin_amdgcn_mfma_f32_16x16x32_bf16(a[m], b[n], acc[m][n], 0, 0, 0);
      __builtin_amdgcn_s_setprio(0);
    }

    __builtin_amdgcn_sched_barrier(0);
    __builtin_amdgcn_s_barrier();              // every wave done READING buf[cur]

    if (t + 2 < NT){
      G2_STAGE((t + 2) * 64, cur);             // overwrite freed buffer
      asm volatile("s_waitcnt vmcnt(6)");      // tile t+1 landed; t+2 stays in flight
    } else {
      asm volatile("s_waitcnt vmcnt(0)");      // tail: drain remaining
    }
    __builtin_amdgcn_sched_barrier(0);
    __builtin_amdgcn_s_barrier();              // every wave's tile t+1 landed
    cur ^= 1;
  }

  #pragma unroll
  for (int m = 0; m < 4; m++){
    int gr0 = m0 + wr * 64 + m * 16 + rq * 4;
    #pragma unroll
    for (int n = 0; n < 4; n++){
      int gc = n0 + wc * 64 + n * 16 + cl;
      #pragma unroll
      for (int rr = 0; rr < 4; rr++){
        if (OUT_BF16) ((u16*)Cout)[(size_t)(gr0 + rr) * N + gc] = f2bf(acc[m][n][rr]);
        else          ((float*)Cout)[(size_t)(gr0 + rr) * N + gc] = acc[m][n][rr];
      }
    }
  }
}

// ---------------- flash attention v6 (champion): deep K+V prefetch ----------

#define STAGE_K(jj, bsel) do {                                                            \
  _Pragma("unroll")                                                                       \
  for (int i_ = 0; i_ < 4; i_++){                                                         \
    int fb_ = (i_ * 4 + wv) * 64;                                                         \
    int p_  = (fb_ + lane) * 16;                                                          \
    int r_ = p_ >> 8; int cb_ = (p_ & 255) ^ ((r_ & 7) << 4);                             \
    gl_lds16(qk + (size_t)(b * LL + (jj) * 64 + r_) * QKN + 2048 + h * HDD + (cb_ >> 1),  \
             &Kb[bsel][fb_ * 8]);                                                         \
  }                                                                                       \
} while(0)

#define STAGE_V(jj, bsel) do {                                                            \
  _Pragma("unroll")                                                                       \
  for (int i_ = 0; i_ < 4; i_++){                                                         \
    int fb_ = (i_ * 4 + wv) * 64;                                                         \
    int p_  = (fb_ + lane) * 16;                                                          \
    int r_ = p_ >> 7; int cb_ = (p_ & 127) ^ ((r_ & 7) << 4);                             \
    gl_lds16(vt + (size_t)(bh * HDD + r_) * LL + (jj) * 64 + (cb_ >> 1),                  \
             &Vb[bsel][fb_ * 8]);                                                         \
  }                                                                                       \
} while(0)

__global__ __launch_bounds__(256, 2) void attn_k(
    const u16* __restrict__ qk, const u16* __restrict__ vt,
    u16* __restrict__ aout)
{
  __shared__ __align__(16) u16 Kb[2][64 * 128];   // K tiles, 2x16KB
  __shared__ __align__(16) u16 Vb[2][128 * 64];   // V^T tiles, 2x16KB
  __shared__ __align__(16) u16 Ps[4][1024];       // per-wave P tile 16x64, 8KB
  const int tid = threadIdx.x, lane = tid & 63, wv = tid >> 6;
  const int bh = blockIdx.x;                      // fast dim -> XCD = bh % 8
  const int pr = blockIdx.y;                      // pair index 0..15
  const int b = bh >> 4, h = bh & 15;
  const int rq = lane >> 4, cl = lane & 15;

  bf16x8 ones;
  #pragma unroll
  for (int i = 0; i < 8; i++) ones[i] = (__bf16)1.0f;
  const f32x4 Z = {0.f, 0.f, 0.f, 0.f};

  int cur = 0;
  STAGE_V(0, 0);                                  // phase-A tile 0 (V older in queue)
  STAGE_K(0, 0);

  #pragma unroll
  for (int ph = 0; ph < 2; ph++){
    const int qt = ph ? pr : (31 - pr);           // 64-row q-tile index
    const int nj = qt + 1;

    bf16x8 qf[4];
    {
      const u16* qb = qk + (size_t)(b * LL + qt * 64 + wv * 16 + cl) * QKN + h * HDD + rq * 8;
      #pragma unroll
      for (int ks = 0; ks < 4; ks++) qf[ks] = *(const bf16x8*)(qb + ks * 32);
    }

    f32x4 acco[8], accl;
    float mst[4];
    #pragma unroll
    for (int n = 0; n < 8; n++) acco[n] = Z;
    accl = Z;
    #pragma unroll
    for (int rr = 0; rr < 4; rr++) mst[rr] = -INFINITY;

    for (int j = 0; j < nj; j++){
      const bool sn = (j + 1 < nj) || (ph == 0);  // stages a next tile this iter
      if (j + 1 < nj){      STAGE_V(j + 1, cur ^ 1); STAGE_K(j + 1, cur ^ 1); }
      else if (ph == 0){    STAGE_V(0,     cur ^ 1); STAGE_K(0,     cur ^ 1); }
      __builtin_amdgcn_sched_barrier(0);
      if (sn) asm volatile("s_waitcnt vmcnt(8)" ::: "memory");  // tile j fully landed
      else    asm volatile("s_waitcnt vmcnt(0)" ::: "memory");
      __builtin_amdgcn_sched_barrier(0);
      __builtin_amdgcn_s_barrier();               // all waves' K(j),V(j) landed
      __builtin_amdgcn_sched_barrier(0);

      // S = Q K^T (16 q-rows x 64 kv per wave)
      f32x4 sv[4];
      {
        const char* KsC = (const char*)&Kb[cur][0];
        #pragma unroll
        for (int ct = 0; ct < 4; ct++) sv[ct] = Z;
        #pragma unroll
        for (int ks = 0; ks < 4; ks++){
          const int kb = ks * 64 + rq * 16;
          #pragma unroll
          for (int ct = 0; ct < 4; ct++){
            int r = ct * 16 + cl;
            bf16x8 bfr = *(const bf16x8*)(KsC + r * 256 + (kb ^ ((r & 7) << 4)));
            sv[ct] = __builtin_amdgcn_mfma_f32_16x16x32_bf16(qf[ks], bfr, sv[ct], 0, 0, 0);
          }
        }
      }

      // softmax (exp2 domain) + P write into own Ps slot (in-wave RAW ordering)
      {
        char* pbase = (char*)&Ps[wv][0];
        const bool msk = (j == qt);                 // diagonal tile only

        float p4[4][4], lmx[4];
        #pragma unroll
        for (int rr = 0; rr < 4; rr++) lmx[rr] = -1e30f;
        const int qg = qt * 64 + wv * 16 + rq * 4;
        #pragma unroll
        for (int ct = 0; ct < 4; ct++){
          int col = j * 64 + ct * 16 + cl;
          #pragma unroll
          for (int rr = 0; rr < 4; rr++){
            float v = sv[ct][rr];                   // already log2-domain
            if (msk && col > qg + rr) v = -1e30f;
            p4[ct][rr] = v;
            lmx[rr] = fmaxf(lmx[rr], v);
          }
        }
        float need = -1e30f;
        #pragma unroll
        for (int rr = 0; rr < 4; rr++) need = fmaxf(need, lmx[rr] - mst[rr]);
        if (__any(need > THR2)){
          float mx[4];
          #pragma unroll
          for (int rr = 0; rr < 4; rr++) mx[rr] = lmx[rr];
          #pragma unroll
          for (int off = 1; off < 16; off <<= 1)
            #pragma unroll
            for (int rr = 0; rr < 4; rr++)
              mx[rr] = fmaxf(mx[rr], __shfl_xor(mx[rr], off, 64));
          #pragma unroll
          for (int rr = 0; rr < 4; rr++){
            float mn  = fmaxf(mst[rr], mx[rr]);
            float fsc = exp2_fast(mst[rr] - mn);
            mst[rr] = mn;
            accl[rr] *= fsc;
            #pragma unroll
            for (int n = 0; n < 8; n++) acco[n][rr] *= fsc;
          }
        }
        #pragma unroll
        for (int ct = 0; ct < 4; ct++)
          #pragma unroll
          for (int rr = 0; rr < 4; rr++){
            float e = exp2_fast(p4[ct][rr] - mst[rr]);
            int wr = rq * 4 + rr;
            *(u16*)(pbase + wr * 128 + (((ct * 16 + cl) * 2) ^ ((wr & 7) << 4))) = f2bf(e);
          }
      }

      // O += P V ; l += P 1  (V already resident; no mid-iter wait)
      {
        const char* VsC = (const char*)&Vb[cur][0];
        char* pbase = (char*)&Ps[wv][0];
        #pragma unroll
        for (int ks = 0; ks < 2; ks++){
          const int kvb = ks * 64 + rq * 16;
          bf16x8 pa = *(const bf16x8*)(pbase + cl * 128 + (kvb ^ ((cl & 7) << 4)));
          accl = __builtin_amdgcn_mfma_f32_16x16x32_bf16(pa, ones, accl, 0, 0, 0);
          #pragma unroll
          for (int n = 0; n < 8; n++){
            int r = n * 16 + cl;
            bf16x8 bfr = *(const bf16x8*)(VsC + r * 128 + (kvb ^ ((r & 7) << 4)));
            acco[n] = __builtin_amdgcn_mfma_f32_16x16x32_bf16(pa, bfr, acco[n], 0, 0, 0);
          }
        }
      }

      __builtin_amdgcn_sched_barrier(0);
      __builtin_amdgcn_s_barrier();               // reads of buf[cur] done before overwrite
      __builtin_amdgcn_sched_barrier(0);
      cur ^= 1;
    }

    // direct write-out
    #pragma unroll
    for (int rr = 0; rr < 4; rr++){
      float inv = 1.0f / accl[rr];
      size_t grow = (size_t)(b * LL + qt * 64 + wv * 16 + rq * 4 + rr);
      #pragma unroll
      for (int n = 0; n < 8; n++)
        aout[grow * HIDD + h * HDD + n * 16 + cl] = f2bf(acco[n][rr] * inv);
    }
  }
}

// ---------------- launcher ----------------

extern "C" void kernel_launch(void* const* d_in, const int* in_sizes, int n_in,
                              void* d_out, int out_size, void* d_ws, size_t ws_size,
                              hipStream_t stream)
{
  const float* x  = (const float*)d_in[0];
  // d_in[1] = mask (causal; applied analytically)
  const float* Wq = (const float*)d_in[2];
  const float* Wk = (const float*)d_in[3];
  const float* Wv = (const float*)d_in[4];
  const float* Wo = (const float*)d_in[5];
  float* out = (float*)d_out;

  if (ws_size < 120586240ull) return;  // need ~115 MB of scratch

  char* ws = (char*)d_ws;
  u16*    xb   = (u16*)(ws);                   // 4096x2048 bf16   (16 MB)
  u16*    Wt   = (u16*)(ws + 16777216ull);     // 6144x2048 bf16   (24 MB) = [Wq|Wk|Wv]^T
  u16*    Wot  = (u16*)(ws + 41943040ull);     // 2048x2048 bf16   ( 8 MB)
  u16*    qk   = (u16*)(ws + 50331648ull);     // 4096x4096 bf16   (32 MB) roped q|k
  u16*    vt   = (u16*)(ws + 83886080ull);     // 32x128x2048 bf16 (16 MB)
  u16*    aout = (u16*)(ws + 100663296ull);    // 4096x2048 bf16   (16 MB)
  float2* rtab = (float2*)(ws + 117440512ull); // 2048x64 float2   ( 1 MB)

  cvt_f32_bf16_k<<<2097152 / 256, 256, 0, stream>>>(x, xb, 2097152);
  rope_table_k<<<131072 / 256, 256, 0, stream>>>(rtab);
  transpose_cvt4_k<<<dim3(32, 32, 4), 256, 0, stream>>>(Wq, Wk, Wv, Wo, Wt, Wot);

  gemm_qkv256_k<<<dim3(6144 / 256, 4096 / 256), 512, 0, stream>>>(xb, Wt, qk, vt, rtab, 2048);

  attn_k<<<dim3(32, 16), 256, 0, stream>>>(qk, vt, aout);

  gemm_bt2_k<0><<<dim3(2048 / 256, 4096 / 128), 512, 0, stream>>>(aout, Wot, out, 4096, 2048, 2048);
}